// Round 3
// baseline (69.030 us; speedup 1.0000x reference)
//
#include <hip/hip_runtime.h>
#include <cstdint>

#define BLOCK 256
#define ROWS 64   // rows per block (one per lane of a wave)

__device__ __forceinline__ float fast_elu(float x) {
    // jax.nn.elu: x>0 ? x : expm1(x)
    return x > 0.0f ? x : __expf(x) - 1.0f;
}

__device__ __forceinline__ float fast_softplus(float x) {
    // numerically stable: max(x,0) + log1p(exp(-|x|))
    return fmaxf(x, 0.0f) + __logf(1.0f + __expf(-fabsf(x)));
}

constexpr int GAS_[76] = {
    0,0,0,0,0,0,0,0,0,0,0,0,0,0,0,0,0,0,0,0,0,0,0,0,0,0,0,0,0,
    1,1,1,1,1,1,1,1,1,1,1,1,1,
    2,2,2,2,2,2,2,2,2,
    3,3,3,
    4,4,4,4,4,4,4,4,4,
    5,5,5,5,5,5,5,5,5,5,5,5,5};
constexpr int CHAN_[76] = {
    0,1,2,3,4,5,6,7,8,9,10,11,12,13,14,15,16,17,18,19,20,21,22,23,24,25,26,27,28,
    0,1,2,17,18,19,20,21,22,25,26,27,28,
    0,1,2,5,6,9,10,13,14,
    0,1,2,
    0,1,2,3,4,7,8,11,12,
    0,1,2,15,16,17,18,19,20,21,22,27,28};

// Run nets [NS, NE): compile-time range so CHAN_/GAS_ indices are constexpr
// (tau stays in registers) and weight addresses are wave-uniform s_loads.
template<int NS, int NE>
__device__ __forceinline__ void run_nets(
    const float* __restrict__ W1, const float* __restrict__ b1,
    const float* __restrict__ W2, const float* __restrict__ b2,
    const float* __restrict__ W3, const float* __restrict__ b3,
    float tpx, float tpy, const float* cg, float* tau)
{
    #pragma unroll
    for (int n = NS; n < NE; ++n) {
        float h1[4];
        #pragma unroll
        for (int o = 0; o < 4; ++o)
            h1[o] = fast_elu(fmaf(tpx, W1[n * 8 + o],
                             fmaf(tpy, W1[n * 8 + 4 + o], b1[n * 4 + o])));
        float h2[4];
        #pragma unroll
        for (int o = 0; o < 4; ++o) {
            float a = b2[n * 4 + o];
            #pragma unroll
            for (int i = 0; i < 4; ++i)
                a = fmaf(h1[i], W2[n * 16 + i * 4 + o], a);
            h2[o] = fast_elu(a);
        }
        float a = b3[n];
        #pragma unroll
        for (int i = 0; i < 4; ++i)
            a = fmaf(h2[i], W3[n * 4 + i], a);
        tau[CHAN_[n]] = fmaf(fast_softplus(a), cg[GAS_[n]], tau[CHAN_[n]]);
    }
}

__global__ void __launch_bounds__(BLOCK)
od_kernel(const float* __restrict__ t_p,
          const float* __restrict__ comp,
          const float* __restrict__ null_lw,
          const float* __restrict__ null_iw,
          const float* __restrict__ W1, const float* __restrict__ b1,
          const float* __restrict__ W2, const float* __restrict__ b2,
          const float* __restrict__ W3, const float* __restrict__ b3,
          const float* __restrict__ W_lw, const float* __restrict__ b_lw,
          const float* __restrict__ W_iw, const float* __restrict__ b_iw,
          float* __restrict__ out, int B)
{
    // 2 partial tau panels (14,848 B): waves 0,1 write; waves 2,3 add into.
    // Occupancy cap becomes the 32-wave/CU limit (8 blocks/CU), not LDS.
    __shared__ float stage[2][ROWS * 29];

    const int wave = threadIdx.x >> 6;
    const int lane = threadIdx.x & 63;
    const int base = blockIdx.x * ROWS;
    const int row  = (base + lane < B) ? (base + lane) : (B - 1);  // clamped load idx

    const float2 tp = *reinterpret_cast<const float2*>(t_p + (size_t)row * 2);
    const float4 ca = *reinterpret_cast<const float4*>(comp + (size_t)row * 8);
    const float2 cbl = *reinterpret_cast<const float2*>(comp + (size_t)row * 8 + 4);
    const float cg[6] = {ca.x, ca.y, ca.z, ca.w, cbl.x, cbl.y};

    float tau[29];
    #pragma unroll
    for (int i = 0; i < 29; ++i) tau[i] = 0.0f;

    // each wave computes a compile-time quarter of the 76 nets for its 64 rows
    switch (wave) {
        case 0: run_nets< 0, 19>(W1, b1, W2, b2, W3, b3, tp.x, tp.y, cg, tau); break;
        case 1: run_nets<19, 38>(W1, b1, W2, b2, W3, b3, tp.x, tp.y, cg, tau); break;
        case 2: run_nets<38, 57>(W1, b1, W2, b2, W3, b3, tp.x, tp.y, cg, tau); break;
        default: run_nets<57, 76>(W1, b1, W2, b2, W3, b3, tp.x, tp.y, cg, tau); break;
    }

    // 2-phase reduction: stride 29 is coprime with 32 banks -> conflict-free.
    if (wave < 2) {
        #pragma unroll
        for (int i = 0; i < 29; ++i) stage[wave][lane * 29 + i] = tau[i];
    }
    __syncthreads();
    if (wave >= 2) {
        float* p = stage[wave - 2];
        #pragma unroll
        for (int i = 0; i < 29; ++i) p[lane * 29 + i] += tau[i];
    }
    __syncthreads();

    const int rem = (B - base < ROWS) ? (B - base) : ROWS;   // valid rows this block
    const int lim = rem * 29;
    const size_t obase = (size_t)base * 29;
    const size_t BN = (size_t)B * 29;

    // ---- output 0: tau_gases = panel0 + panel1; flat coalesced ----
    for (int idx = threadIdx.x; idx < lim; idx += BLOCK)
        out[obase + idx] = stage[0][idx] + stage[1][idx];

    // ---- outputs 1,2: lw / iw (no cross-wave dependence; direct coalesced) ----
    for (int idx = threadIdx.x; idx < lim; idx += BLOCK) {
        const int r  = idx / 29;          // magic-mul div
        const int ch = idx - r * 29;
        const int grow = base + r;
        const float nl = null_lw[grow];
        const float ni = null_iw[grow];
        const float c6 = comp[(size_t)grow * 8 + 6];
        const float c7 = comp[(size_t)grow * 8 + 7];
        out[BN + obase + idx]     = fast_softplus(fmaf(nl, W_lw[ch], b_lw[ch])) * c6;
        out[2 * BN + obase + idx] = fast_softplus(fmaf(ni, W_iw[ch], b_iw[ch])) * c7;
    }
}

extern "C" void kernel_launch(void* const* d_in, const int* in_sizes, int n_in,
                              void* d_out, int out_size, void* d_ws, size_t ws_size,
                              hipStream_t stream) {
    const float* t_p     = (const float*)d_in[0];
    const float* comp    = (const float*)d_in[1];
    const float* null_lw = (const float*)d_in[2];
    const float* null_iw = (const float*)d_in[3];
    const float* W1      = (const float*)d_in[4];
    const float* b1      = (const float*)d_in[5];
    const float* W2      = (const float*)d_in[6];
    const float* b2      = (const float*)d_in[7];
    const float* W3      = (const float*)d_in[8];
    const float* b3      = (const float*)d_in[9];
    const float* W_lw    = (const float*)d_in[10];
    const float* b_lw    = (const float*)d_in[11];
    const float* W_iw    = (const float*)d_in[12];
    const float* b_iw    = (const float*)d_in[13];
    float* out = (float*)d_out;

    const int B = in_sizes[0] / 2;
    const int blocks = (B + ROWS - 1) / ROWS;
    od_kernel<<<blocks, BLOCK, 0, stream>>>(t_p, comp, null_lw, null_iw,
                                            W1, b1, W2, b2, W3, b3,
                                            W_lw, b_lw, W_iw, b_iw, out, B);
}

// Round 4
// 60.641 us; speedup vs baseline: 1.1384x; 1.1384x over previous
//
#include <hip/hip_runtime.h>
#include <cstdint>

#define BLOCK 256
#define ROWS 64    // rows per block (one per lane of a wave)
#define NREC 40    // floats per preprocessed net record (160 B)

__device__ __forceinline__ float exp2_fast(float x) { return __builtin_amdgcn_exp2f(x); }
__device__ __forceinline__ float log2_fast(float x) { return __builtin_amdgcn_logf(x); }

#define LN2 0.6931471805599453f
#define L2E 1.4426950408889634f

constexpr int GAS_[76] = {
    0,0,0,0,0,0,0,0,0,0,0,0,0,0,0,0,0,0,0,0,0,0,0,0,0,0,0,0,0,
    1,1,1,1,1,1,1,1,1,1,1,1,1,
    2,2,2,2,2,2,2,2,2,
    3,3,3,
    4,4,4,4,4,4,4,4,4,
    5,5,5,5,5,5,5,5,5,5,5,5,5};
constexpr int CHAN_[76] = {
    0,1,2,3,4,5,6,7,8,9,10,11,12,13,14,15,16,17,18,19,20,21,22,23,24,25,26,27,28,
    0,1,2,17,18,19,20,21,22,25,26,27,28,
    0,1,2,5,6,9,10,13,14,
    0,1,2,
    0,1,2,3,4,7,8,11,12,
    0,1,2,15,16,17,18,19,20,21,22,27,28};

// ---- prep kernel: build per-net records, all in log2e-scaled domain ----
// layout per net (NREC floats):
//   [0..7]  W1s  = W1 * L2E            (i*4+o)
//   [8..11] B1s  = b1 * L2E
//   [12..27] W2s = W2 * L2E            (i*4+o)
//   [28..31] B2a = (b2 - sum_i W2[i][o]) * L2E   (bias absorbs H=h+1 shift)
//   [32..35] W3s = W3 * L2E
//   [36]     B3a = (b3 - sum_i W3[i]) * L2E
__global__ void __launch_bounds__(128)
prep_kernel(const float* __restrict__ W1, const float* __restrict__ b1,
            const float* __restrict__ W2, const float* __restrict__ b2,
            const float* __restrict__ W3, const float* __restrict__ b3,
            float* __restrict__ rec)
{
    const int n = threadIdx.x;
    if (n >= 76) return;
    float* r = rec + n * NREC;
    #pragma unroll
    for (int k = 0; k < 8; ++k) r[k] = W1[n * 8 + k] * L2E;
    #pragma unroll
    for (int o = 0; o < 4; ++o) r[8 + o] = b1[n * 4 + o] * L2E;
    #pragma unroll
    for (int k = 0; k < 16; ++k) r[12 + k] = W2[n * 16 + k] * L2E;
    #pragma unroll
    for (int o = 0; o < 4; ++o) {
        float s = 0.0f;
        #pragma unroll
        for (int i = 0; i < 4; ++i) s += W2[n * 16 + i * 4 + o];
        r[28 + o] = (b2[n * 4 + o] - s) * L2E;
    }
    float s3 = 0.0f;
    #pragma unroll
    for (int i = 0; i < 4; ++i) { r[32 + i] = W3[n * 4 + i] * L2E; s3 += W3[n * 4 + i]; }
    r[36] = (b3[n] - s3) * L2E;
    r[37] = 0.0f; r[38] = 0.0f; r[39] = 0.0f;
}

// H = elu(a)+1 = max(a+1, 2^min(as,0)) where as = a*log2e. 4 VALU ops.
__device__ __forceinline__ float elu_h(float as) {
    return fmaxf(fmaf(as, LN2, 1.0f), exp2_fast(fminf(as, 0.0f)));
}

// Run nets [NS, NE): compile-time range so CHAN_/GAS_ indices are constexpr
// and record offsets are wave-uniform s_loads from one contiguous base.
template<int NS, int NE>
__device__ __forceinline__ void run_nets(
    const float* __restrict__ rec, float tpx, float tpy,
    const float* cgl2 /* cg * ln2 */, float* tau)
{
    #pragma unroll
    for (int n = NS; n < NE; ++n) {
        const float* __restrict__ R = rec + n * NREC;
        float H1[4];
        #pragma unroll
        for (int o = 0; o < 4; ++o)
            H1[o] = elu_h(fmaf(tpx, R[o], fmaf(tpy, R[4 + o], R[8 + o])));
        float H2[4];
        #pragma unroll
        for (int o = 0; o < 4; ++o) {
            float a = R[28 + o];
            #pragma unroll
            for (int i = 0; i < 4; ++i)
                a = fmaf(H1[i], R[12 + i * 4 + o], a);
            H2[o] = elu_h(a);
        }
        float a3 = R[36];
        #pragma unroll
        for (int i = 0; i < 4; ++i)
            a3 = fmaf(H2[i], R[32 + i], a3);
        // softplus(a3/L2E) in log2 units: max(a3,0) + log2(1 + 2^-|a3|)
        const float sp = fmaxf(a3, 0.0f) + log2_fast(1.0f + exp2_fast(-fabsf(a3)));
        tau[CHAN_[n]] = fmaf(sp, cgl2[GAS_[n]], tau[CHAN_[n]]);  // cgl2 = cg*ln2
    }
}

__device__ __forceinline__ float softplus_nat(float x) {
    // natural-units softplus via native exp2/log2
    return fmaxf(x, 0.0f) + LN2 * log2_fast(1.0f + exp2_fast(-fabsf(x) * L2E));
}

template<bool EXACT>
__global__ void __launch_bounds__(BLOCK)
od_kernel(const float* __restrict__ t_p,
          const float* __restrict__ comp,
          const float* __restrict__ null_lw,
          const float* __restrict__ null_iw,
          const float* __restrict__ rec,
          const float* __restrict__ W_lw, const float* __restrict__ b_lw,
          const float* __restrict__ W_iw, const float* __restrict__ b_iw,
          float* __restrict__ out, int B)
{
    __shared__ float stage[2][ROWS * 29];

    const int wave = threadIdx.x >> 6;
    const int lane = threadIdx.x & 63;
    const int base = blockIdx.x * ROWS;
    const int row  = EXACT ? (base + lane)
                           : ((base + lane < B) ? (base + lane) : (B - 1));

    const float2 tp = *reinterpret_cast<const float2*>(t_p + (size_t)row * 2);
    const float4 ca = *reinterpret_cast<const float4*>(comp + (size_t)row * 8);
    const float2 cbl = *reinterpret_cast<const float2*>(comp + (size_t)row * 8 + 4);
    const float cgl2[6] = {ca.x * LN2, ca.y * LN2, ca.z * LN2,
                           ca.w * LN2, cbl.x * LN2, cbl.y * LN2};

    float tau[29];
    #pragma unroll
    for (int i = 0; i < 29; ++i) tau[i] = 0.0f;

    switch (wave) {
        case 0: run_nets< 0, 19>(rec, tp.x, tp.y, cgl2, tau); break;
        case 1: run_nets<19, 38>(rec, tp.x, tp.y, cgl2, tau); break;
        case 2: run_nets<38, 57>(rec, tp.x, tp.y, cgl2, tau); break;
        default: run_nets<57, 76>(rec, tp.x, tp.y, cgl2, tau); break;
    }

    // 2-phase reduction; stride 29 coprime with 32 banks -> conflict-free.
    if (wave < 2) {
        #pragma unroll
        for (int i = 0; i < 29; ++i) stage[wave][lane * 29 + i] = tau[i];
    }
    __syncthreads();
    if (wave >= 2) {
        float* p = stage[wave - 2];
        #pragma unroll
        for (int i = 0; i < 29; ++i) p[lane * 29 + i] += tau[i];
    }
    __syncthreads();

    const size_t obase = (size_t)base * 29;
    const size_t BN = (size_t)B * 29;
    const int lim = EXACT ? (ROWS * 29)
                          : (((B - base < ROWS) ? (B - base) : ROWS) * 29);

    // single merged epilogue: all 3 outputs share idx -> (r,ch) decode
    #pragma unroll
    for (int k = 0; k < (ROWS * 29 + BLOCK - 1) / BLOCK; ++k) {
        const int idx = threadIdx.x + k * BLOCK;
        if ((k < (ROWS * 29) / BLOCK || idx < ROWS * 29) && (EXACT || idx < lim)) {
            out[obase + idx] = stage[0][idx] + stage[1][idx];
            const int r  = idx / 29;          // magic-mul div
            const int ch = idx - r * 29;
            const int grow = base + r;
            const float nl = null_lw[grow];
            const float ni = null_iw[grow];
            const float c6 = comp[(size_t)grow * 8 + 6];
            const float c7 = comp[(size_t)grow * 8 + 7];
            out[BN + obase + idx]     = softplus_nat(fmaf(nl, W_lw[ch], b_lw[ch])) * c6;
            out[2 * BN + obase + idx] = softplus_nat(fmaf(ni, W_iw[ch], b_iw[ch])) * c7;
        }
    }
}

extern "C" void kernel_launch(void* const* d_in, const int* in_sizes, int n_in,
                              void* d_out, int out_size, void* d_ws, size_t ws_size,
                              hipStream_t stream) {
    const float* t_p     = (const float*)d_in[0];
    const float* comp    = (const float*)d_in[1];
    const float* null_lw = (const float*)d_in[2];
    const float* null_iw = (const float*)d_in[3];
    const float* W1      = (const float*)d_in[4];
    const float* b1      = (const float*)d_in[5];
    const float* W2      = (const float*)d_in[6];
    const float* b2      = (const float*)d_in[7];
    const float* W3      = (const float*)d_in[8];
    const float* b3      = (const float*)d_in[9];
    const float* W_lw    = (const float*)d_in[10];
    const float* b_lw    = (const float*)d_in[11];
    const float* W_iw    = (const float*)d_in[12];
    const float* b_iw    = (const float*)d_in[13];
    float* out = (float*)d_out;
    float* rec = (float*)d_ws;   // 76*40*4 = 12,160 B

    const int B = in_sizes[0] / 2;

    prep_kernel<<<1, 128, 0, stream>>>(W1, b1, W2, b2, W3, b3, rec);

    const int blocks = (B + ROWS - 1) / ROWS;
    if (B % ROWS == 0)
        od_kernel<true><<<blocks, BLOCK, 0, stream>>>(t_p, comp, null_lw, null_iw,
                                                      rec, W_lw, b_lw, W_iw, b_iw, out, B);
    else
        od_kernel<false><<<blocks, BLOCK, 0, stream>>>(t_p, comp, null_lw, null_iw,
                                                       rec, W_lw, b_lw, W_iw, b_iw, out, B);
}